// Round 8
// baseline (143.633 us; speedup 1.0000x reference)
//
#include <hip/hip_runtime.h>
#include <math.h>

constexpr int B = 64;
constexpr int L = 4096;
constexpr int C = 256;
constexpr int H = 32;

constexpr int NCH = 32;          // chunks per batch
constexpr int ROWS = L / NCH;    // 128 rows per chunk (128 KB)

typedef float v4f __attribute__((ext_vector_type(4)));

// ---------------- Pass 1: per-(batch,chunk) column sums ----------------
// grid = B*NCH = 2048 blocks, 256 threads. Thread t owns float4-column
// (t&63), row-phase (t>>6). nt loads + 8-deep batch (same recipe that took
// the scale pass from 5.4 -> 6.0 TB/s in R7).
__global__ __launch_bounds__(256) void se_reduce(const float* __restrict__ in,
                                                 float* __restrict__ partial) {
    const int b = blockIdx.x / NCH;
    const int chunk = blockIdx.x % NCH;
    const int t = threadIdx.x;
    const int c4 = t & 63;
    const int r0 = t >> 6;

    const v4f* base = reinterpret_cast<const v4f*>(
        in + (size_t)b * L * C + (size_t)chunk * ROWS * C);

    v4f acc = (v4f)(0.f);
    // Thread rows: r0 + 4k, k = 0..31. Four groups of 8 outstanding loads.
    #pragma unroll
    for (int grp = 0; grp < 4; ++grp) {
        const size_t i0 = (size_t)(r0 + grp * 32) * (C / 4) + c4;
        v4f v[8];
        #pragma unroll
        for (int j = 0; j < 8; ++j)
            v[j] = __builtin_nontemporal_load(&base[i0 + (size_t)j * 4 * (C / 4)]);
        #pragma unroll
        for (int j = 0; j < 8; ++j)
            acc += v[j];
    }

    __shared__ v4f red[4][C / 4];
    red[r0][c4] = acc;
    __syncthreads();
    if (r0 == 0) {
        v4f s = red[0][c4] + red[1][c4] + red[2][c4] + red[3][c4];
        reinterpret_cast<v4f*>(partial + (size_t)blockIdx.x * C)[c4] = s;
    }
}

// ---------------- Pass 2: fold partials + tiny gate MLP ----------------
// grid = B, block = 256. (Identical to R3/R7.)
__global__ __launch_bounds__(256) void se_gate(const float* __restrict__ partial,
                                               const float* __restrict__ w1,
                                               const float* __restrict__ b1,
                                               const float* __restrict__ w2,
                                               const float* __restrict__ b2,
                                               float* __restrict__ g) {
    const int b = blockIdx.x;
    const int t = threadIdx.x;

    __shared__ float sm[C];
    __shared__ float em[H];

    float acc = 0.f;
    const float* p = partial + (size_t)b * NCH * C + t;
    #pragma unroll 8
    for (int k = 0; k < NCH; ++k) acc += p[(size_t)k * C];
    sm[t] = acc * (1.0f / (float)L);
    __syncthreads();

    if (t < H) {
        float a1 = b1[t];
        #pragma unroll 8
        for (int c = 0; c < C; ++c) a1 += sm[c] * w1[c * H + t];
        em[t] = fmaxf(a1, 0.0f);
    }
    __syncthreads();

    float a2 = b2[t];
    #pragma unroll
    for (int h = 0; h < H; ++h) a2 += em[h] * w2[h * C + t];
    g[b * C + t] = 1.0f / (1.0f + expf(-a2));
}

// ---------------- Pass 3: broadcast scale ----------------
// Identical to R7: chunk-mapped, gv hoisted, nt loads + nt stores, 8-deep.
__global__ __launch_bounds__(256) void se_scale(const v4f* __restrict__ in,
                                                const float* __restrict__ g,
                                                v4f* __restrict__ out) {
    const int b = blockIdx.x / NCH;
    const int chunk = blockIdx.x % NCH;
    const int t = threadIdx.x;
    const int c4 = t & 63;
    const int r0 = t >> 6;  // 0..3

    const size_t base = (size_t)b * L * (C / 4)
                      + (size_t)chunk * ROWS * (C / 4) + c4;
    const v4f gv = reinterpret_cast<const v4f*>(g)[b * (C / 4) + c4];

    #pragma unroll
    for (int grp = 0; grp < 4; ++grp) {
        const size_t i0 = base + (size_t)(r0 + grp * 32) * (C / 4);
        v4f v[8];
        #pragma unroll
        for (int j = 0; j < 8; ++j)
            v[j] = __builtin_nontemporal_load(&in[i0 + (size_t)j * 4 * (C / 4)]);
        #pragma unroll
        for (int j = 0; j < 8; ++j)
            __builtin_nontemporal_store(v[j] * gv, &out[i0 + (size_t)j * 4 * (C / 4)]);
    }
}

extern "C" void kernel_launch(void* const* d_in, const int* in_sizes, int n_in,
                              void* d_out, int out_size, void* d_ws, size_t ws_size,
                              hipStream_t stream) {
    const float* in = (const float*)d_in[0];
    const float* w1 = (const float*)d_in[1];
    const float* b1 = (const float*)d_in[2];
    const float* w2 = (const float*)d_in[3];
    const float* b2 = (const float*)d_in[4];
    float* out = (float*)d_out;

    float* partial = (float*)d_ws;               // B*NCH*C floats = 2 MB
    float* g = partial + (size_t)B * NCH * C;    // B*C floats = 64 KB

    se_reduce<<<B * NCH, 256, 0, stream>>>(in, partial);
    se_gate<<<B, 256, 0, stream>>>(partial, w1, b1, w2, b2, g);
    se_scale<<<B * NCH, 256, 0, stream>>>(
        reinterpret_cast<const v4f*>(in), g, reinterpret_cast<v4f*>(out));
}

// Round 9
// 137.475 us; speedup vs baseline: 1.0448x; 1.0448x over previous
//
#include <hip/hip_runtime.h>
#include <math.h>

constexpr int B = 64;
constexpr int L = 4096;
constexpr int C = 256;
constexpr int H = 32;

constexpr int NCH = 32;          // chunks per batch
constexpr int ROWS = L / NCH;    // 128 rows per chunk (128 KB)

typedef float v4f __attribute__((ext_vector_type(4)));

// ---------------- Pass 1: per-(batch,chunk) column sums ----------------
// grid = B*NCH = 2048 blocks, 256 threads. PLAIN loads (they allocate the
// input into L3, which the nt-only scale pass then hits — R8 proved nt
// loads here cost 6 µs in the scale pass). 8-deep batch kept for ILP.
__global__ __launch_bounds__(256) void se_reduce(const float* __restrict__ in,
                                                 float* __restrict__ partial) {
    const int b = blockIdx.x / NCH;
    const int chunk = blockIdx.x % NCH;
    const int t = threadIdx.x;
    const int c4 = t & 63;
    const int r0 = t >> 6;

    const v4f* base = reinterpret_cast<const v4f*>(
        in + (size_t)b * L * C + (size_t)chunk * ROWS * C);

    v4f acc = (v4f)(0.f);
    // Thread rows: r0 + 4k, k = 0..31. Four groups of 8 outstanding loads.
    #pragma unroll
    for (int grp = 0; grp < 4; ++grp) {
        const size_t i0 = (size_t)(r0 + grp * 32) * (C / 4) + c4;
        v4f v[8];
        #pragma unroll
        for (int j = 0; j < 8; ++j)
            v[j] = base[i0 + (size_t)j * 4 * (C / 4)];
        #pragma unroll
        for (int j = 0; j < 8; ++j)
            acc += v[j];
    }

    __shared__ v4f red[4][C / 4];
    red[r0][c4] = acc;
    __syncthreads();
    if (r0 == 0) {
        v4f s = red[0][c4] + red[1][c4] + red[2][c4] + red[3][c4];
        reinterpret_cast<v4f*>(partial + (size_t)blockIdx.x * C)[c4] = s;
    }
}

// ---------------- Pass 2: fold partials + tiny gate MLP ----------------
// grid = B, block = 256. (Identical to R3/R7.)
__global__ __launch_bounds__(256) void se_gate(const float* __restrict__ partial,
                                               const float* __restrict__ w1,
                                               const float* __restrict__ b1,
                                               const float* __restrict__ w2,
                                               const float* __restrict__ b2,
                                               float* __restrict__ g) {
    const int b = blockIdx.x;
    const int t = threadIdx.x;

    __shared__ float sm[C];
    __shared__ float em[H];

    float acc = 0.f;
    const float* p = partial + (size_t)b * NCH * C + t;
    #pragma unroll 8
    for (int k = 0; k < NCH; ++k) acc += p[(size_t)k * C];
    sm[t] = acc * (1.0f / (float)L);
    __syncthreads();

    if (t < H) {
        float a1 = b1[t];
        #pragma unroll 8
        for (int c = 0; c < C; ++c) a1 += sm[c] * w1[c * H + t];
        em[t] = fmaxf(a1, 0.0f);
    }
    __syncthreads();

    float a2 = b2[t];
    #pragma unroll
    for (int h = 0; h < H; ++h) a2 += em[h] * w2[h * C + t];
    g[b * C + t] = 1.0f / (1.0f + expf(-a2));
}

// ---------------- Pass 3: broadcast scale ----------------
// Identical to R7: chunk-mapped, gv hoisted, nt loads (hit L3 if resident,
// never allocate/pollute) + nt stores (write stream bypasses cache), 8-deep.
__global__ __launch_bounds__(256) void se_scale(const v4f* __restrict__ in,
                                                const float* __restrict__ g,
                                                v4f* __restrict__ out) {
    const int b = blockIdx.x / NCH;
    const int chunk = blockIdx.x % NCH;
    const int t = threadIdx.x;
    const int c4 = t & 63;
    const int r0 = t >> 6;  // 0..3

    const size_t base = (size_t)b * L * (C / 4)
                      + (size_t)chunk * ROWS * (C / 4) + c4;
    const v4f gv = reinterpret_cast<const v4f*>(g)[b * (C / 4) + c4];

    #pragma unroll
    for (int grp = 0; grp < 4; ++grp) {
        const size_t i0 = base + (size_t)(r0 + grp * 32) * (C / 4);
        v4f v[8];
        #pragma unroll
        for (int j = 0; j < 8; ++j)
            v[j] = __builtin_nontemporal_load(&in[i0 + (size_t)j * 4 * (C / 4)]);
        #pragma unroll
        for (int j = 0; j < 8; ++j)
            __builtin_nontemporal_store(v[j] * gv, &out[i0 + (size_t)j * 4 * (C / 4)]);
    }
}

extern "C" void kernel_launch(void* const* d_in, const int* in_sizes, int n_in,
                              void* d_out, int out_size, void* d_ws, size_t ws_size,
                              hipStream_t stream) {
    const float* in = (const float*)d_in[0];
    const float* w1 = (const float*)d_in[1];
    const float* b1 = (const float*)d_in[2];
    const float* w2 = (const float*)d_in[3];
    const float* b2 = (const float*)d_in[4];
    float* out = (float*)d_out;

    float* partial = (float*)d_ws;               // B*NCH*C floats = 2 MB
    float* g = partial + (size_t)B * NCH * C;    // B*C floats = 64 KB

    se_reduce<<<B * NCH, 256, 0, stream>>>(in, partial);
    se_gate<<<B, 256, 0, stream>>>(partial, w1, b1, w2, b2, g);
    se_scale<<<B * NCH, 256, 0, stream>>>(
        reinterpret_cast<const v4f*>(in), g, reinterpret_cast<v4f*>(out));
}